// Round 13
// baseline (284.931 us; speedup 1.0000x reference)
//
#include <hip/hip_runtime.h>
#include <cstdint>
#include <cstddef>

// DCNv2 x2 (B=2, C=O=256, H=W=96, k=3), fully fused per layer.
// R24: dfconv v6 (counted-vmcnt rounds) cured the per-round vmcnt(0) drain:
// 78->58.7us. offconv has the same disease (2 __syncthreads drains/round,
// ~3250cy/round == one round's staging at the latency-MLP rate). offconv_v2
// ports the structure: fully double-buffered LDS ([db][kg], 110.6KB), ONE
// raw s_barrier per round (lgkmcnt(0)-only + sched_barrier per rule #18),
// cur/nxt register-set rotation (round r: write cur=pf(r+1) -> buf[db^1],
// issue pf(r+2) -> nxt, MFMA buf[db]). Staging loads are register-destined
// so the compiler's dataflow waitcnt gives exact counted waits (~vmcnt(6))
// with no manual counting; loads span the raw barrier.
// dfconv v6 + transpose/preps byte-identical to R23 (control arms).
// k' = kk*256 + c. XCD swizzle: blockIdx%8 = XCD.

#define KTOT 2304
#define PXB  9216

typedef __attribute__((ext_vector_type(8))) short bf16x8;
typedef __attribute__((ext_vector_type(4))) float f32x4;

static __device__ __forceinline__ unsigned short f2bf(float f) {
    union { float f; unsigned int u; } v; v.f = f;
    unsigned int r = (v.u + 0x7FFFu + ((v.u >> 16) & 1u)) >> 16;
    return (unsigned short)r;
}
static __device__ __forceinline__ float bf2f(unsigned short h) {
    union { unsigned int u; float f; } v; v.u = ((unsigned int)h) << 16;
    return v.f;
}
// unpack 8 bf16 (uint4) -> 8 fp32; 1 bit-op per element
static __device__ __forceinline__ void unpack8(uint4 u, float* f) {
    union { unsigned int u; float f; } t;
    t.u = u.x << 16;         f[0] = t.f;
    t.u = u.x & 0xffff0000u; f[1] = t.f;
    t.u = u.y << 16;         f[2] = t.f;
    t.u = u.y & 0xffff0000u; f[3] = t.f;
    t.u = u.z << 16;         f[4] = t.f;
    t.u = u.z & 0xffff0000u; f[5] = t.f;
    t.u = u.w << 16;         f[6] = t.f;
    t.u = u.w & 0xffff0000u; f[7] = t.f;
}

// ---------------------------------------------------------------------------
// NCHW -> NHWC transpose, hi/lo bf16 outputs
// ---------------------------------------------------------------------------
__global__ __launch_bounds__(256) void transpose_kernel(const float* __restrict__ in,
                                                        unsigned short* __restrict__ outH,
                                                        unsigned short* __restrict__ outL) {
    __shared__ float tile[64][65];
    const int hw0 = blockIdx.x * 64;
    const int c0  = blockIdx.y * 64;
    const int b   = blockIdx.z;
    const int lx  = threadIdx.x & 63;
    const int ly  = threadIdx.x >> 6;
#pragma unroll
    for (int i = 0; i < 16; ++i) {
        int cl = ly + i * 4;
        tile[cl][lx] = in[(size_t)(b * 256 + c0 + cl) * PXB + hw0 + lx];
    }
    __syncthreads();
#pragma unroll
    for (int i = 0; i < 16; ++i) {
        int hwl = ly + i * 4;
        float v = tile[lx][hwl];
        size_t oi = ((size_t)b * PXB + hw0 + hwl) * 256 + c0 + lx;
        unsigned short hi = f2bf(v);
        outH[oi] = hi;
        outL[oi] = f2bf(v - bf2f(hi));
    }
}

// ---------------------------------------------------------------------------
// Main weight prep: w[o][c][kk] fp32 -> wA[o][k'=kk*256+c] bf16
// ---------------------------------------------------------------------------
__global__ __launch_bounds__(256) void prep_w_kernel(const float* __restrict__ w,
                                                     unsigned short* __restrict__ wA) {
    int idx = blockIdx.x * 256 + threadIdx.x;   // 256*2304
    int o = idx / KTOT;
    int k = idx - o * KTOT;
    int kk = k >> 8;
    int c  = k & 255;
    wA[idx] = f2bf(w[o * KTOT + c * 9 + kk]);
}

// ---------------------------------------------------------------------------
// Offset weight prep (split): rows 27..32 zero. hi = bf16(w), lo = bf16(w-hi).
// ---------------------------------------------------------------------------
__global__ __launch_bounds__(256) void prep_woff_kernel(const float* __restrict__ w,
                                                        unsigned short* __restrict__ wH,
                                                        unsigned short* __restrict__ wL) {
    int idx = blockIdx.x * 256 + threadIdx.x;   // 32*2304
    int o = idx / KTOT;
    int k = idx - o * KTOT;
    int kk = k >> 8;
    int c  = k & 255;
    float f = (o < 27) ? w[o * KTOT + c * 9 + kk] : 0.0f;
    unsigned short hi = f2bf(f);
    wH[idx] = hi;
    wL[idx] = f2bf(f - bf2f(hi));
}

// ---------------------------------------------------------------------------
// Fused offset conv v2: M=32(27) x N=64px x K=2304, split-bf16 3-term.
// Counted-wait rounds: dbuf LDS [db][kg], ONE raw s_barrier/round,
// cur/nxt register rotation. Compiler dataflow waitcnt = counted vmcnt.
// ---------------------------------------------------------------------------
__global__ __launch_bounds__(512) void offconv_v2(const unsigned short* __restrict__ xH,
                                                  const unsigned short* __restrict__ xL,
                                                  const unsigned short* __restrict__ AH,
                                                  const unsigned short* __restrict__ AL,
                                                  const float* __restrict__ bias,
                                                  float* __restrict__ om) {
    // [db][kg] panels, ushort units
    __shared__ __attribute__((aligned(16))) unsigned short AsH[2 * 2 * 32 * 72];
    __shared__ __attribute__((aligned(16))) unsigned short AsL[2 * 2 * 32 * 72];
    __shared__ __attribute__((aligned(16))) unsigned short BsH[2 * 2 * 64 * 72];
    __shared__ __attribute__((aligned(16))) unsigned short BsL[2 * 2 * 64 * 72];

    const int tid  = threadIdx.x;
    const int kg   = tid >> 8;
    const int tl   = tid & 255;
    const int lane = tid & 63;
    const int wq   = (tid >> 6) & 3;
    const int quad = lane >> 4, l16 = lane & 15;
    const int g    = blockIdx.x;            // 288
    const int nb   = (g & 7) * 36 + (g >> 3);
    const int n0   = nb * 64;
    const int b    = n0 / PXB;
    const int hw0  = n0 - b * PXB;

    f32x4 acc[2];
#pragma unroll
    for (int mt = 0; mt < 2; ++mt) acc[mt] = (f32x4)0.0f;

    const int arow = tl >> 3, akg = tl & 7;
    const int px0 = tl >> 3,          cg0 = tl & 7;
    const int px1 = (256 + tl) >> 3,  cg1 = tl & 7;

    // load pf(it) into a 6-reg set
    auto pfL = [&](int it, uint4& rAH, uint4& rAL, uint4& rB0H, uint4& rB0L,
                   uint4& rB1H, uint4& rB1L) {
        const int kt = kg * 18 + it;
        const int kk = kt >> 2, c0 = (kt & 3) * 64;
        const int dy = kk / 3 - 1, dx = kk - (kk / 3) * 3 - 1;
        size_t ai = (size_t)arow * KTOT + kt * 64 + akg * 8;
        rAH = *(const uint4*)&AH[ai];
        rAL = *(const uint4*)&AL[ai];
        {
            int hw = hw0 + px0;
            int h = hw / 96, w = hw - h * 96;
            int y = h + dy, x = w + dx;
            uint4 hv = make_uint4(0u, 0u, 0u, 0u), lv = hv;
            if (((unsigned)y < 96u) && ((unsigned)x < 96u)) {
                size_t bi = ((size_t)b * PXB + y * 96 + x) * 256 + c0 + cg0 * 8;
                hv = *(const uint4*)&xH[bi];
                lv = *(const uint4*)&xL[bi];
            }
            rB0H = hv; rB0L = lv;
        }
        {
            int hw = hw0 + px1;
            int h = hw / 96, w = hw - h * 96;
            int y = h + dy, x = w + dx;
            uint4 hv = make_uint4(0u, 0u, 0u, 0u), lv = hv;
            if (((unsigned)y < 96u) && ((unsigned)x < 96u)) {
                size_t bi = ((size_t)b * PXB + y * 96 + x) * 256 + c0 + cg1 * 8;
                hv = *(const uint4*)&xH[bi];
                lv = *(const uint4*)&xL[bi];
            }
            rB1H = hv; rB1L = lv;
        }
    };
    // write a set into LDS buffer db
    auto writeSet = [&](int db, uint4 sAH, uint4 sAL, uint4 sB0H, uint4 sB0L,
                        uint4 sB1H, uint4 sB1L) {
        const int ab = (db * 2 + kg) * 2304;   // 32*72
        const int bb = (db * 2 + kg) * 4608;   // 64*72
        *(uint4*)&AsH[ab + arow * 72 + akg * 8] = sAH;
        *(uint4*)&AsL[ab + arow * 72 + akg * 8] = sAL;
        *(uint4*)&BsH[bb + px0 * 72 + cg0 * 8] = sB0H;
        *(uint4*)&BsL[bb + px0 * 72 + cg0 * 8] = sB0L;
        *(uint4*)&BsH[bb + px1 * 72 + cg1 * 8] = sB1H;
        *(uint4*)&BsL[bb + px1 * 72 + cg1 * 8] = sB1L;
    };

    uint4 cAH, cAL, cB0H, cB0L, cB1H, cB1L;     // set to write this round
    uint4 nAH, nAL, nB0H, nB0L, nB1H, nB1L;     // set in flight

    // ---- prologue: pf(0)->cur, pf(1)->nxt; write pf(0) -> buf0 ----
    pfL(0, cAH, cAL, cB0H, cB0L, cB1H, cB1L);
    pfL(1, nAH, nAL, nB0H, nB0L, nB1H, nB1L);
    writeSet(0, cAH, cAL, cB0H, cB0L, cB1H, cB1L);   // compiler waits cur only
    cAH = nAH; cAL = nAL; cB0H = nB0H; cB0L = nB0L; cB1H = nB1H; cB1L = nB1L;
    asm volatile("s_waitcnt lgkmcnt(0)" ::: "memory");
    __builtin_amdgcn_sched_barrier(0);
    __builtin_amdgcn_s_barrier();

    // ---- main loop: 18 rounds, ONE raw barrier each ----
    for (int it = 0; it < 18; ++it) {
        const int db = it & 1;

        // 1. issue pf(it+2) into nxt (stays in flight across this round)
        if (it <= 15)
            pfL(it + 2, nAH, nAL, nB0H, nB0L, nB1H, nB1L);

        // 2. write cur (= pf(it+1)) -> buf[db^1]; compiler inserts the
        //    counted vmcnt for cur's loads (nxt's 6 remain outstanding)
        if (it <= 16)
            writeSet(db ^ 1, cAH, cAL, cB0H, cB0L, cB1H, cB1L);

        // 3. MFMA on buf[db]
        {
            const int ab = (db * 2 + kg) * 2304;
            const int bb = (db * 2 + kg) * 4608;
#pragma unroll
            for (int ks = 0; ks < 2; ++ks) {
                bf16x8 ah[2], al[2], bh, bl;
#pragma unroll
                for (int mt = 0; mt < 2; ++mt) {
                    ah[mt] = *(const bf16x8*)&AsH[ab + (mt * 16 + l16) * 72 + ks * 32 + quad * 8];
                    al[mt] = *(const bf16x8*)&AsL[ab + (mt * 16 + l16) * 72 + ks * 32 + quad * 8];
                }
                bh = *(const bf16x8*)&BsH[bb + (wq * 16 + l16) * 72 + ks * 32 + quad * 8];
                bl = *(const bf16x8*)&BsL[bb + (wq * 16 + l16) * 72 + ks * 32 + quad * 8];
#pragma unroll
                for (int mt = 0; mt < 2; ++mt) {
                    acc[mt] = __builtin_amdgcn_mfma_f32_16x16x32_bf16(ah[mt], bh, acc[mt], 0, 0, 0);
                    acc[mt] = __builtin_amdgcn_mfma_f32_16x16x32_bf16(ah[mt], bl, acc[mt], 0, 0, 0);
                    acc[mt] = __builtin_amdgcn_mfma_f32_16x16x32_bf16(al[mt], bh, acc[mt], 0, 0, 0);
                }
            }
        }

        // 4. rotate register sets
        cAH = nAH; cAL = nAL; cB0H = nB0H; cB0L = nB0L; cB1H = nB1H; cB1L = nB1L;

        // 5. ds ops visible; raw barrier (loads span it)
        asm volatile("s_waitcnt lgkmcnt(0)" ::: "memory");
        __builtin_amdgcn_sched_barrier(0);
        __builtin_amdgcn_s_barrier();
    }

    // ---- in-block split-K reduction: kg1 publishes, kg0 adds + stores ----
    float* red = (float*)BsH;
    __syncthreads();
    if (kg == 1) {
#pragma unroll
        for (int mt = 0; mt < 2; ++mt)
#pragma unroll
            for (int r = 0; r < 4; ++r)
                red[wq * 512 + mt * 256 + quad * 64 + r * 16 + l16] = acc[mt][r];
    }
    __syncthreads();
    if (kg == 0) {
#pragma unroll
        for (int mt = 0; mt < 2; ++mt)
#pragma unroll
            for (int r = 0; r < 4; ++r) {
                float v = acc[mt][r] + red[wq * 512 + mt * 256 + quad * 64 + r * 16 + l16];
                int m = mt * 16 + quad * 4 + r;
                int n = wq * 16 + l16;
                if (m < 27)
                    om[(size_t)(b * 27 + m) * PXB + hw0 + n] = v + bias[m];
            }
    }
}

// ---------------------------------------------------------------------------
// Fused deformable conv v6 (both layers): M=256 x N=72px (pad 80),
// 36 rounds x K=64, GRID = 256. Counted-vmcnt rounds. (R23 verbatim)
// ---------------------------------------------------------------------------
__global__ __launch_bounds__(512) void dfconv_v6(const unsigned short* __restrict__ xB,
                                                 const float* __restrict__ om,
                                                 const unsigned short* __restrict__ A,
                                                 float* __restrict__ out,
                                                 unsigned short* __restrict__ outH,
                                                 unsigned short* __restrict__ outL,
                                                 int out_mode) {
    __shared__ __attribute__((aligned(16))) char smem[104128];
    unsigned short* BsD  = (unsigned short*)(smem + 65536);
    unsigned short* goff = (unsigned short*)(smem + 88576);
    float*          gwt  = (float*)(smem + 93760);

    const int tid  = threadIdx.x;
    const int wv   = tid >> 6;
    const int lane = tid & 63;
    const int quad = lane >> 4, l16 = lane & 15;
    const int g    = blockIdx.x;            // 256
    const int nb   = (g & 7) * 32 + (g >> 3);
    const int b    = nb >> 7;
    const int hw0  = (nb & 127) * 72;

    for (int task = tid; task < 648; task += 512) {
        int px = task / 9;
        int kk = task - px * 9;
        int hw = hw0 + px;
        int h = hw / 96, w = hw - h * 96;
        const float* omp = om + (size_t)b * 27 * PXB + hw;
        float dyv = omp[(size_t)(2 * kk) * PXB];
        float dxv = omp[(size_t)(2 * kk + 1) * PXB];
        float mv  = omp[(size_t)(18 + kk) * PXB];
        float mk  = 1.0f / (1.0f + __expf(-mv));

        float ys = (float)(h + (kk / 3) - 1) + dyv;
        float xs = (float)(w + (kk - (kk / 3) * 3) - 1) + dxv;
        float fy = floorf(ys), fx = floorf(xs);
        int iy = (int)fy, ix = (int)fx;
        float wy1 = ys - fy, wx1 = xs - fx;
        float wy0 = 1.0f - wy1, wx0 = 1.0f - wx1;
        bool yv0 = (unsigned)iy < 96u, yv1 = (unsigned)(iy + 1) < 96u;
        bool xv0 = (unsigned)ix < 96u, xv1 = (unsigned)(ix + 1) < 96u;
        int y0 = min(max(iy, 0), 95),     y1 = min(max(iy + 1, 0), 95);
        int x0 = min(max(ix, 0), 95),     x1 = min(max(ix + 1, 0), 95);
        int gg = task * 4;
        goff[gg + 0] = (unsigned short)(y0 * 96 + x0);
        goff[gg + 1] = (unsigned short)(y0 * 96 + x1);
        goff[gg + 2] = (unsigned short)(y1 * 96 + x0);
        goff[gg + 3] = (unsigned short)(y1 * 96 + x1);
        gwt[gg + 0] = (yv0 && xv0) ? mk * wy0 * wx0 : 0.0f;
        gwt[gg + 1] = (yv0 && xv1) ? mk * wy0 * wx1 : 0.0f;
        gwt[gg + 2] = (yv1 && xv0) ? mk * wy1 * wx0 : 0.0f;
        gwt[gg + 3] = (yv1 && xv1) ? mk * wy1 * wx1 : 0.0f;
    }
    for (int i = tid; i < 576; i += 512) {
        int buf = i / 288, rem = i - buf * 288;
        int row = 72 + rem / 36, col2 = (rem - (rem / 36) * 36) * 2;
        *(unsigned int*)&BsD[buf * 5760 + row * 72 + col2] = 0u;
    }
    __syncthreads();

    const int px  = tid >> 3;
    const int cg  = tid & 7;
    const int px2 = 64 + (tid >> 3);
    const unsigned short* xbase  = xB + (size_t)b * PXB * 256 + cg * 8;

    const int arl = lane >> 3;
    const int akg = (lane & 7) ^ arl;

    f32x4 acc[2][5];
#pragma unroll
    for (int mt = 0; mt < 2; ++mt)
#pragma unroll
        for (int nt = 0; nt < 5; ++nt) acc[mt][nt] = (f32x4)0.0f;

    auto dmaA = [&](int kt, int buf) {
#pragma unroll
        for (int s = 0; s < 4; ++s) {
            const unsigned short* src =
                A + (size_t)(wv * 32 + s * 8 + arl) * KTOT + kt * 64 + akg * 8;
            char* dst = smem + buf * 32768 + wv * 4096 + s * 1024;
            __builtin_amdgcn_global_load_lds(
                (const __attribute__((address_space(1))) unsigned int*)src,
                (__attribute__((address_space(3))) unsigned int*)dst, 16, 0, 0);
        }
    };
    auto loadC = [&](int kt, uint4& c0r, uint4& c1r, uint4& c2r, uint4& c3r,
                     float4& wtr, int pxl) {
        const int tap = kt >> 2, cb0 = (kt & 3) * 64;
        int gg = (pxl * 9 + tap) * 4;
        ushort4 o4 = *(const ushort4*)&goff[gg];
        wtr = *(const float4*)&gwt[gg];
        const unsigned short* cb = xbase + cb0;
        c0r = *(const uint4*)(cb + (size_t)o4.x * 256);
        c1r = *(const uint4*)(cb + (size_t)o4.y * 256);
        c2r = *(const uint4*)(cb + (size_t)o4.z * 256);
        c3r = *(const uint4*)(cb + (size_t)o4.w * 256);
    };
    auto interpC = [&](uint4 c0r, uint4 c1r, uint4 c2r, uint4 c3r, float4 wtr,
                       unsigned short* Bw, int pxl) {
        float f0[8], f1[8], f2[8], f3[8];
        unpack8(c0r, f0); unpack8(c1r, f1); unpack8(c2r, f2); unpack8(c3r, f3);
        unsigned short res[8];
#pragma unroll
        for (int j = 0; j < 8; ++j)
            res[j] = f2bf(wtr.x * f0[j] + wtr.y * f1[j] + wtr.z * f2[j] + wtr.w * f3[j]);
        *(uint4*)&Bw[pxl * 72 + cg * 8] = *(uint4*)res;
    };

    uint4 cc0, cc1, cc2, cc3; float4 cwt;
    uint4 nn0, nn1, nn2, nn3; float4 nwt;
    uint4 dc0, dc1, dc2, dc3; float4 dwt;
    uint4 dn0, dn1, dn2, dn3; float4 dnwt;
    loadC(0, cc0, cc1, cc2, cc3, cwt, px);
    if (tid < 64) loadC(0, dc0, dc1, dc2, dc3, dwt, px2);
    loadC(1, nn0, nn1, nn2, nn3, nwt, px);
    if (tid < 64) loadC(1, dn0, dn1, dn2, dn3, dnwt, px2);
    dmaA(0, 0);
    __builtin_amdgcn_sched_barrier(0);
    if (wv == 0) { asm volatile("s_waitcnt vmcnt(12)" ::: "memory"); }
    else         { asm volatile("s_waitcnt vmcnt(8)"  ::: "memory"); }
    __builtin_amdgcn_sched_barrier(0);
    interpC(cc0, cc1, cc2, cc3, cwt, BsD, px);
    if (tid < 64) interpC(dc0, dc1, dc2, dc3, dwt, BsD, px2);
    cc0 = nn0; cc1 = nn1; cc2 = nn2; cc3 = nn3; cwt = nwt;
    if (tid < 64) { dc0 = dn0; dc1 = dn1; dc2 = dn2; dc3 = dn3; dwt = dnwt; }
    asm volatile("s_waitcnt lgkmcnt(0)" ::: "memory");
    __builtin_amdgcn_sched_barrier(0);
    __builtin_amdgcn_s_barrier();

    for (int r = 0; r < 36; ++r) {
        const int cur = r & 1;

        if (r <= 33) {
            loadC(r + 2, nn0, nn1, nn2, nn3, nwt, px);
            if (tid < 64) loadC(r + 2, dn0, dn1, dn2, dn3, dnwt, px2);
        }
        if (r <= 34) dmaA(r + 1, cur ^ 1);

        __builtin_amdgcn_sched_barrier(0);
        if (r <= 33) {
            if (wv == 0) { asm volatile("s_waitcnt vmcnt(12)" ::: "memory"); }
            else         { asm volatile("s_waitcnt vmcnt(8)"  ::: "memory"); }
        } else if (r == 34) {
            asm volatile("s_waitcnt vmcnt(4)" ::: "memory");
        } else {
            asm volatile("s_waitcnt vmcnt(0)" ::: "memory");
        }
        __builtin_amdgcn_sched_barrier(0);

        {
            const char* Ac = smem + cur * 32768 + wv * 4096;
            const int sw0 = ((quad ^ (l16 & 7)) * 16);
            const int sw1 = (((4 + quad) ^ (l16 & 7)) * 16);
            bf16x8 af00 = *(const bf16x8*)(Ac + l16 * 128 + sw0);
            bf16x8 af01 = *(const bf16x8*)(Ac + (16 + l16) * 128 + sw0);
            bf16x8 af10 = *(const bf16x8*)(Ac + l16 * 128 + sw1);
            bf16x8 af11 = *(const bf16x8*)(Ac + (16 + l16) * 128 + sw1);
            const unsigned short* Br = BsD + cur * 5760;
#pragma unroll
            for (int nt = 0; nt < 5; ++nt) {
                bf16x8 b0 = *(const bf16x8*)&Br[(nt * 16 + l16) * 72 + quad * 8];
                acc[0][nt] = __builtin_amdgcn_mfma_f32_16x16x32_bf16(af00, b0, acc[0][nt], 0, 0, 0);
                acc[1][nt] = __builtin_amdgcn_mfma_f32_16x16x32_bf16(af01, b0, acc[1][nt], 0, 0, 0);
            }
#pragma unroll
            for (int nt = 0; nt < 5; ++nt) {
                bf16x8 b1 = *(const bf16x8*)&Br[(nt * 16 + l16) * 72 + 32 + quad * 8];
                acc[0][nt] = __builtin_amdgcn_mfma_f32_16x16x32_bf16(af10, b1, acc[0][nt], 0, 0, 0);
                acc[1][nt] = __builtin_amdgcn_mfma_f32_16x16x32_bf16(af11, b1, acc[1][nt], 0, 0, 0);
            }
        }

        if (r <= 34) {
            unsigned short* Bw = BsD + (cur ^ 1) * 5760;
            interpC(cc0, cc1, cc2, cc3, cwt, Bw, px);
            if (tid < 64) interpC(dc0, dc1, dc2, dc3, dwt, Bw, px2);
            cc0 = nn0; cc1 = nn1; cc2 = nn2; cc3 = nn3; cwt = nwt;
            if (tid < 64) { dc0 = dn0; dc1 = dn1; dc2 = dn2; dc3 = dn3; dwt = dnwt; }
        }

        asm volatile("s_waitcnt lgkmcnt(0)" ::: "memory");
        __builtin_amdgcn_sched_barrier(0);
        __builtin_amdgcn_s_barrier();
    }

    asm volatile("s_waitcnt vmcnt(0) lgkmcnt(0)" ::: "memory");
    __syncthreads();

    float* tileS = (float*)smem;
    if (out_mode == 0) {
#pragma unroll
        for (int pass = 0; pass < 4; ++pass) {
            if ((wv >> 1) == pass) {
#pragma unroll
                for (int mt = 0; mt < 2; ++mt)
#pragma unroll
                    for (int nt = 0; nt < 5; ++nt)
#pragma unroll
                        for (int rr = 0; rr < 4; ++rr) {
                            int ml = (wv & 1) * 32 + mt * 16 + quad * 4 + rr;
                            int n  = nt * 16 + l16;
                            tileS[ml * 80 + n] = fmaxf(acc[mt][nt][rr], 0.0f);
                        }
            }
            __syncthreads();
#pragma unroll
            for (int j = 0; j < 3; ++j) {
                int idx = j * 512 + tid;
                if (idx < 1152) {
                    int row = idx / 18, q = idx - row * 18;
                    *(float4*)&out[(size_t)(b * 256 + pass * 64 + row) * PXB + hw0 + q * 4] =
                        *(const float4*)&tileS[row * 80 + q * 4];
                }
            }
            __syncthreads();
        }
    } else {
#pragma unroll
        for (int pass = 0; pass < 5; ++pass) {
#pragma unroll
            for (int mt = 0; mt < 2; ++mt) {
                f32x4 v = acc[mt][pass];
                v[0] = fmaxf(v[0], 0.f); v[1] = fmaxf(v[1], 0.f);
                v[2] = fmaxf(v[2], 0.f); v[3] = fmaxf(v[3], 0.f);
                *(f32x4*)&tileS[l16 * 264 + wv * 32 + mt * 16 + quad * 4] = v;
            }
            __syncthreads();
            const int cnt = (pass < 4) ? 1024 : 512;
#pragma unroll
            for (int j = 0; j < 2; ++j) {
                int idx = j * 512 + tid;
                if (idx < cnt) {
                    int pxl = idx >> 6, ln = idx & 63;
                    float4 v = *(const float4*)&tileS[pxl * 264 + ln * 4];
                    size_t oi = ((size_t)b * PXB + hw0 + pass * 16 + pxl) * 256 + ln * 4;
                    unsigned short hv[4], lv[4];
#pragma unroll
                    for (int e = 0; e < 4; ++e) {
                        float fe = (e == 0) ? v.x : (e == 1) ? v.y : (e == 2) ? v.z : v.w;
                        hv[e] = f2bf(fe);
                        lv[e] = f2bf(fe - bf2f(hv[e]));
                    }
                    *(ushort4*)&outH[oi] = *(ushort4*)hv;
                    *(ushort4*)&outL[oi] = *(ushort4*)lv;
                }
            }
            __syncthreads();
        }
    }
}

// ---------------------------------------------------------------------------
extern "C" void kernel_launch(void* const* d_in, const int* in_sizes, int n_in,
                              void* d_out, int out_size, void* d_ws, size_t ws_size,
                              hipStream_t stream) {
    const float* x     = (const float*)d_in[0];
    const float* woff0 = (const float*)d_in[1];
    const float* boff0 = (const float*)d_in[2];
    const float* w0    = (const float*)d_in[3];
    const float* woff1 = (const float*)d_in[4];
    const float* boff1 = (const float*)d_in[5];
    const float* w1    = (const float*)d_in[6];
    float* out = (float*)d_out;

    char* p = (char*)d_ws;
    float* om  = (float*)p;  p += (size_t)2 * 27 * PXB * 4;               // 2.0 MB
    unsigned short* xh  = (unsigned short*)p; p += (size_t)2 * 256 * PXB * 2;  // 9.4 MB
    unsigned short* xl  = (unsigned short*)p; p += (size_t)2 * 256 * PXB * 2;  // 9.4 MB
    unsigned short* h1h = (unsigned short*)p; p += (size_t)2 * 256 * PXB * 2;  // 9.4 MB
    unsigned short* h1l = (unsigned short*)p; p += (size_t)2 * 256 * PXB * 2;  // 9.4 MB
    unsigned short* wA0 = (unsigned short*)p; p += (size_t)256 * KTOT * 2;
    unsigned short* wA1 = (unsigned short*)p; p += (size_t)256 * KTOT * 2;
    unsigned short* wH0 = (unsigned short*)p; p += (size_t)32 * KTOT * 2;
    unsigned short* wL0 = (unsigned short*)p; p += (size_t)32 * KTOT * 2;
    unsigned short* wH1 = (unsigned short*)p; p += (size_t)32 * KTOT * 2;
    unsigned short* wL1 = (unsigned short*)p; p += (size_t)32 * KTOT * 2;

    hipLaunchKernelGGL(transpose_kernel, dim3(PXB / 64, 4, 2), dim3(256), 0, stream, x, xh, xl);
    hipLaunchKernelGGL(prep_w_kernel, dim3(256 * KTOT / 256), dim3(256), 0, stream, w0, wA0);
    hipLaunchKernelGGL(prep_w_kernel, dim3(256 * KTOT / 256), dim3(256), 0, stream, w1, wA1);
    hipLaunchKernelGGL(prep_woff_kernel, dim3(32 * KTOT / 256), dim3(256), 0, stream, woff0, wH0, wL0);
    hipLaunchKernelGGL(prep_woff_kernel, dim3(32 * KTOT / 256), dim3(256), 0, stream, woff1, wH1, wL1);

    // Layer 0: x -> h1 (NHWC hi/lo bf16)
    hipLaunchKernelGGL(offconv_v2, dim3(288), dim3(512), 0, stream, xh, xl, wH0, wL0, boff0, om);
    hipLaunchKernelGGL(dfconv_v6, dim3(256), dim3(512), 0, stream, xh, om, wA0,
                       (float*)nullptr, h1h, h1l, 1);

    // Layer 1: h1 -> out (NCHW fp32)
    hipLaunchKernelGGL(offconv_v2, dim3(288), dim3(512), 0, stream, h1h, h1l, wH1, wL1, boff1, om);
    hipLaunchKernelGGL(dfconv_v6, dim3(256), dim3(512), 0, stream, h1h, om, wA1,
                       out, (unsigned short*)nullptr, (unsigned short*)nullptr, 0);
}

// Round 14
// 255.618 us; speedup vs baseline: 1.1147x; 1.1147x over previous
//
#include <hip/hip_runtime.h>
#include <cstdint>
#include <cstddef>

// DCNv2 x2 (B=2, C=O=256, H=W=96, k=3), fully fused per layer.
// R25: R24's offconv_v2 regression = occupancy (110.6KB LDS -> 1 blk/CU,
// lockstep 512 thr, grid-288 tail), not the counted-wait structure.
// offconv_v3: 256-thr blocks, grid 576, NO split-K (sequential K, 36 rounds
// x K=64; each of 4 waves owns one (mt,nt) 16x16 tile -> acc=4 VGPR, no
// LDS reduction, direct stores). LDS 36.9KB -> 4 blocks/CU, ALL 576 blocks
// resident (16 waves/CU hide every barrier). Counted-wait skeleton kept:
// cur/nxt reg rotation, one raw s_barrier/round, lgkmcnt(0)-only,
// register-destined staging loads (compiler dataflow waitcnt keeps nxt in
// flight across the barrier). launch_bounds(256,4) caps VGPR 128 (est ~100).
// dfconv v6 + transpose/preps byte-identical to R23.
// k' = kk*256 + c. XCD swizzle: blockIdx%8 = XCD.

#define KTOT 2304
#define PXB  9216

typedef __attribute__((ext_vector_type(8))) short bf16x8;
typedef __attribute__((ext_vector_type(4))) float f32x4;

static __device__ __forceinline__ unsigned short f2bf(float f) {
    union { float f; unsigned int u; } v; v.f = f;
    unsigned int r = (v.u + 0x7FFFu + ((v.u >> 16) & 1u)) >> 16;
    return (unsigned short)r;
}
static __device__ __forceinline__ float bf2f(unsigned short h) {
    union { unsigned int u; float f; } v; v.u = ((unsigned int)h) << 16;
    return v.f;
}
// unpack 8 bf16 (uint4) -> 8 fp32; 1 bit-op per element
static __device__ __forceinline__ void unpack8(uint4 u, float* f) {
    union { unsigned int u; float f; } t;
    t.u = u.x << 16;         f[0] = t.f;
    t.u = u.x & 0xffff0000u; f[1] = t.f;
    t.u = u.y << 16;         f[2] = t.f;
    t.u = u.y & 0xffff0000u; f[3] = t.f;
    t.u = u.z << 16;         f[4] = t.f;
    t.u = u.z & 0xffff0000u; f[5] = t.f;
    t.u = u.w << 16;         f[6] = t.f;
    t.u = u.w & 0xffff0000u; f[7] = t.f;
}

// ---------------------------------------------------------------------------
// NCHW -> NHWC transpose, hi/lo bf16 outputs
// ---------------------------------------------------------------------------
__global__ __launch_bounds__(256) void transpose_kernel(const float* __restrict__ in,
                                                        unsigned short* __restrict__ outH,
                                                        unsigned short* __restrict__ outL) {
    __shared__ float tile[64][65];
    const int hw0 = blockIdx.x * 64;
    const int c0  = blockIdx.y * 64;
    const int b   = blockIdx.z;
    const int lx  = threadIdx.x & 63;
    const int ly  = threadIdx.x >> 6;
#pragma unroll
    for (int i = 0; i < 16; ++i) {
        int cl = ly + i * 4;
        tile[cl][lx] = in[(size_t)(b * 256 + c0 + cl) * PXB + hw0 + lx];
    }
    __syncthreads();
#pragma unroll
    for (int i = 0; i < 16; ++i) {
        int hwl = ly + i * 4;
        float v = tile[lx][hwl];
        size_t oi = ((size_t)b * PXB + hw0 + hwl) * 256 + c0 + lx;
        unsigned short hi = f2bf(v);
        outH[oi] = hi;
        outL[oi] = f2bf(v - bf2f(hi));
    }
}

// ---------------------------------------------------------------------------
// Main weight prep: w[o][c][kk] fp32 -> wA[o][k'=kk*256+c] bf16
// ---------------------------------------------------------------------------
__global__ __launch_bounds__(256) void prep_w_kernel(const float* __restrict__ w,
                                                     unsigned short* __restrict__ wA) {
    int idx = blockIdx.x * 256 + threadIdx.x;   // 256*2304
    int o = idx / KTOT;
    int k = idx - o * KTOT;
    int kk = k >> 8;
    int c  = k & 255;
    wA[idx] = f2bf(w[o * KTOT + c * 9 + kk]);
}

// ---------------------------------------------------------------------------
// Offset weight prep (split): rows 27..32 zero. hi = bf16(w), lo = bf16(w-hi).
// ---------------------------------------------------------------------------
__global__ __launch_bounds__(256) void prep_woff_kernel(const float* __restrict__ w,
                                                        unsigned short* __restrict__ wH,
                                                        unsigned short* __restrict__ wL) {
    int idx = blockIdx.x * 256 + threadIdx.x;   // 32*2304
    int o = idx / KTOT;
    int k = idx - o * KTOT;
    int kk = k >> 8;
    int c  = k & 255;
    float f = (o < 27) ? w[o * KTOT + c * 9 + kk] : 0.0f;
    unsigned short hi = f2bf(f);
    wH[idx] = hi;
    wL[idx] = f2bf(f - bf2f(hi));
}

// ---------------------------------------------------------------------------
// Fused offset conv v3: M=32(27) x N=32px x K=2304 sequential, grid 576 x
// 256 thr. 4 waves = (mt,nt) 16x16 tiles. Counted-wait rounds, dbuf LDS
// (36.9KB -> 4 blocks/CU). Direct stores (no split-K reduction).
// ---------------------------------------------------------------------------
__global__ __launch_bounds__(256, 4) void offconv_v3(const unsigned short* __restrict__ xH,
                                                     const unsigned short* __restrict__ xL,
                                                     const unsigned short* __restrict__ AH,
                                                     const unsigned short* __restrict__ AL,
                                                     const float* __restrict__ bias,
                                                     float* __restrict__ om) {
    __shared__ __attribute__((aligned(16))) unsigned short AsH[2][32 * 72];
    __shared__ __attribute__((aligned(16))) unsigned short AsL[2][32 * 72];
    __shared__ __attribute__((aligned(16))) unsigned short BsH[2][32 * 72];
    __shared__ __attribute__((aligned(16))) unsigned short BsL[2][32 * 72];

    const int tid  = threadIdx.x;
    const int wv   = tid >> 6;              // 0..3
    const int lane = tid & 63;
    const int quad = lane >> 4, l16 = lane & 15;
    const int mt   = wv & 1;                // M tile (rows mt*16..+16)
    const int nt   = wv >> 1;               // N tile (px nt*16..+16)
    // XCD swizzle: g%8 = xcd owns n-blocks [xcd*72, xcd*72+72)
    const int g    = blockIdx.x;            // 576
    const int nb   = (g & 7) * 72 + (g >> 3);
    const int n0   = nb * 32;
    const int b    = n0 / PXB;
    const int hw0  = n0 - b * PXB;

    const int arow = tid >> 3, acol = tid & 7;   // A staging: 32 rows x 8 gran
    const int px   = tid >> 3, cg   = tid & 7;   // B staging: 32 px x 8 gran

    f32x4 acc = (f32x4)0.0f;

    // load round kt's staging set into registers
    auto pfL = [&](int kt, uint4& rAH, uint4& rAL, uint4& rBH, uint4& rBL) {
        const int kk = kt >> 2, c0 = (kt & 3) * 64;
        const int dy = kk / 3 - 1, dx = kk - (kk / 3) * 3 - 1;
        size_t ai = (size_t)arow * KTOT + kt * 64 + acol * 8;
        rAH = *(const uint4*)&AH[ai];
        rAL = *(const uint4*)&AL[ai];
        int hw = hw0 + px;
        int h = hw / 96, w = hw - h * 96;
        int y = h + dy, x = w + dx;
        uint4 hv = make_uint4(0u, 0u, 0u, 0u), lv = hv;
        if (((unsigned)y < 96u) && ((unsigned)x < 96u)) {
            size_t bi = ((size_t)b * PXB + y * 96 + x) * 256 + c0 + cg * 8;
            hv = *(const uint4*)&xH[bi];
            lv = *(const uint4*)&xL[bi];
        }
        rBH = hv; rBL = lv;
    };
    auto writeSet = [&](int db, uint4 sAH, uint4 sAL, uint4 sBH, uint4 sBL) {
        *(uint4*)&AsH[db][arow * 72 + acol * 8] = sAH;
        *(uint4*)&AsL[db][arow * 72 + acol * 8] = sAL;
        *(uint4*)&BsH[db][px * 72 + cg * 8]     = sBH;
        *(uint4*)&BsL[db][px * 72 + cg * 8]     = sBL;
    };

    uint4 cAH, cAL, cBH, cBL;    // set to write this round (= pf(r+1) later)
    uint4 nAH, nAL, nBH, nBL;    // set in flight

    // ---- prologue: pf(0)->cur, pf(1)->nxt; write pf(0) -> buf0 ----
    pfL(0, cAH, cAL, cBH, cBL);
    pfL(1, nAH, nAL, nBH, nBL);
    writeSet(0, cAH, cAL, cBH, cBL);       // compiler waits cur's loads only
    cAH = nAH; cAL = nAL; cBH = nBH; cBL = nBL;
    asm volatile("s_waitcnt lgkmcnt(0)" ::: "memory");
    __builtin_amdgcn_sched_barrier(0);
    __builtin_amdgcn_s_barrier();

    // ---- main loop: 36 rounds, ONE raw barrier each ----
    for (int r = 0; r < 36; ++r) {
        const int db = r & 1;

        // 1. issue pf(r+2) into nxt (stays in flight across this round)
        if (r <= 33)
            pfL(r + 2, nAH, nAL, nBH, nBL);

        // 2. write cur (= pf(r+1)) -> buf[db^1]; compiler's dataflow vmcnt
        //    drains cur only (nxt's 4 loads remain outstanding)
        if (r <= 34)
            writeSet(db ^ 1, cAH, cAL, cBH, cBL);

        // 3. MFMA on buf[db]: 2 ks x 3 split-terms
#pragma unroll
        for (int ks = 0; ks < 2; ++ks) {
            bf16x8 ah = *(const bf16x8*)&AsH[db][(mt * 16 + l16) * 72 + ks * 32 + quad * 8];
            bf16x8 al = *(const bf16x8*)&AsL[db][(mt * 16 + l16) * 72 + ks * 32 + quad * 8];
            bf16x8 bh = *(const bf16x8*)&BsH[db][(nt * 16 + l16) * 72 + ks * 32 + quad * 8];
            bf16x8 bl = *(const bf16x8*)&BsL[db][(nt * 16 + l16) * 72 + ks * 32 + quad * 8];
            acc = __builtin_amdgcn_mfma_f32_16x16x32_bf16(ah, bh, acc, 0, 0, 0);
            acc = __builtin_amdgcn_mfma_f32_16x16x32_bf16(ah, bl, acc, 0, 0, 0);
            acc = __builtin_amdgcn_mfma_f32_16x16x32_bf16(al, bh, acc, 0, 0, 0);
        }

        // 4. rotate register sets
        cAH = nAH; cAL = nAL; cBH = nBH; cBL = nBL;

        // 5. ds ops visible; raw barrier (loads span it)
        asm volatile("s_waitcnt lgkmcnt(0)" ::: "memory");
        __builtin_amdgcn_sched_barrier(0);
        __builtin_amdgcn_s_barrier();
    }

    // ---- direct store: m = mt*16 + quad*4 + rr (m<27), n = nt*16 + l16 ----
#pragma unroll
    for (int rr = 0; rr < 4; ++rr) {
        int m = mt * 16 + quad * 4 + rr;
        int n = nt * 16 + l16;
        if (m < 27)
            om[(size_t)(b * 27 + m) * PXB + hw0 + n] = acc[rr] + bias[m];
    }
}

// ---------------------------------------------------------------------------
// Fused deformable conv v6 (both layers): M=256 x N=72px (pad 80),
// 36 rounds x K=64, GRID = 256. Counted-vmcnt rounds. (R23 verbatim)
// ---------------------------------------------------------------------------
__global__ __launch_bounds__(512) void dfconv_v6(const unsigned short* __restrict__ xB,
                                                 const float* __restrict__ om,
                                                 const unsigned short* __restrict__ A,
                                                 float* __restrict__ out,
                                                 unsigned short* __restrict__ outH,
                                                 unsigned short* __restrict__ outL,
                                                 int out_mode) {
    __shared__ __attribute__((aligned(16))) char smem[104128];
    unsigned short* BsD  = (unsigned short*)(smem + 65536);
    unsigned short* goff = (unsigned short*)(smem + 88576);
    float*          gwt  = (float*)(smem + 93760);

    const int tid  = threadIdx.x;
    const int wv   = tid >> 6;
    const int lane = tid & 63;
    const int quad = lane >> 4, l16 = lane & 15;
    const int g    = blockIdx.x;            // 256
    const int nb   = (g & 7) * 32 + (g >> 3);
    const int b    = nb >> 7;
    const int hw0  = (nb & 127) * 72;

    for (int task = tid; task < 648; task += 512) {
        int px = task / 9;
        int kk = task - px * 9;
        int hw = hw0 + px;
        int h = hw / 96, w = hw - h * 96;
        const float* omp = om + (size_t)b * 27 * PXB + hw;
        float dyv = omp[(size_t)(2 * kk) * PXB];
        float dxv = omp[(size_t)(2 * kk + 1) * PXB];
        float mv  = omp[(size_t)(18 + kk) * PXB];
        float mk  = 1.0f / (1.0f + __expf(-mv));

        float ys = (float)(h + (kk / 3) - 1) + dyv;
        float xs = (float)(w + (kk - (kk / 3) * 3) - 1) + dxv;
        float fy = floorf(ys), fx = floorf(xs);
        int iy = (int)fy, ix = (int)fx;
        float wy1 = ys - fy, wx1 = xs - fx;
        float wy0 = 1.0f - wy1, wx0 = 1.0f - wx1;
        bool yv0 = (unsigned)iy < 96u, yv1 = (unsigned)(iy + 1) < 96u;
        bool xv0 = (unsigned)ix < 96u, xv1 = (unsigned)(ix + 1) < 96u;
        int y0 = min(max(iy, 0), 95),     y1 = min(max(iy + 1, 0), 95);
        int x0 = min(max(ix, 0), 95),     x1 = min(max(ix + 1, 0), 95);
        int gg = task * 4;
        goff[gg + 0] = (unsigned short)(y0 * 96 + x0);
        goff[gg + 1] = (unsigned short)(y0 * 96 + x1);
        goff[gg + 2] = (unsigned short)(y1 * 96 + x0);
        goff[gg + 3] = (unsigned short)(y1 * 96 + x1);
        gwt[gg + 0] = (yv0 && xv0) ? mk * wy0 * wx0 : 0.0f;
        gwt[gg + 1] = (yv0 && xv1) ? mk * wy0 * wx1 : 0.0f;
        gwt[gg + 2] = (yv1 && xv0) ? mk * wy1 * wx0 : 0.0f;
        gwt[gg + 3] = (yv1 && xv1) ? mk * wy1 * wx1 : 0.0f;
    }
    for (int i = tid; i < 576; i += 512) {
        int buf = i / 288, rem = i - buf * 288;
        int row = 72 + rem / 36, col2 = (rem - (rem / 36) * 36) * 2;
        *(unsigned int*)&BsD[buf * 5760 + row * 72 + col2] = 0u;
    }
    __syncthreads();

    const int px  = tid >> 3;
    const int cg  = tid & 7;
    const int px2 = 64 + (tid >> 3);
    const unsigned short* xbase  = xB + (size_t)b * PXB * 256 + cg * 8;

    const int arl = lane >> 3;
    const int akg = (lane & 7) ^ arl;

    f32x4 acc[2][5];
#pragma unroll
    for (int mt = 0; mt < 2; ++mt)
#pragma unroll
        for (int nt = 0; nt < 5; ++nt) acc[mt][nt] = (f32x4)0.0f;

    auto dmaA = [&](int kt, int buf) {
#pragma unroll
        for (int s = 0; s < 4; ++s) {
            const unsigned short* src =
                A + (size_t)(wv * 32 + s * 8 + arl) * KTOT + kt * 64 + akg * 8;
            char* dst = smem + buf * 32768 + wv * 4096 + s * 1024;
            __builtin_amdgcn_global_load_lds(
                (const __attribute__((address_space(1))) unsigned int*)src,
                (__attribute__((address_space(3))) unsigned int*)dst, 16, 0, 0);
        }
    };
    auto loadC = [&](int kt, uint4& c0r, uint4& c1r, uint4& c2r, uint4& c3r,
                     float4& wtr, int pxl) {
        const int tap = kt >> 2, cb0 = (kt & 3) * 64;
        int gg = (pxl * 9 + tap) * 4;
        ushort4 o4 = *(const ushort4*)&goff[gg];
        wtr = *(const float4*)&gwt[gg];
        const unsigned short* cb = xbase + cb0;
        c0r = *(const uint4*)(cb + (size_t)o4.x * 256);
        c1r = *(const uint4*)(cb + (size_t)o4.y * 256);
        c2r = *(const uint4*)(cb + (size_t)o4.z * 256);
        c3r = *(const uint4*)(cb + (size_t)o4.w * 256);
    };
    auto interpC = [&](uint4 c0r, uint4 c1r, uint4 c2r, uint4 c3r, float4 wtr,
                       unsigned short* Bw, int pxl) {
        float f0[8], f1[8], f2[8], f3[8];
        unpack8(c0r, f0); unpack8(c1r, f1); unpack8(c2r, f2); unpack8(c3r, f3);
        unsigned short res[8];
#pragma unroll
        for (int j = 0; j < 8; ++j)
            res[j] = f2bf(wtr.x * f0[j] + wtr.y * f1[j] + wtr.z * f2[j] + wtr.w * f3[j]);
        *(uint4*)&Bw[pxl * 72 + cg * 8] = *(uint4*)res;
    };

    uint4 cc0, cc1, cc2, cc3; float4 cwt;
    uint4 nn0, nn1, nn2, nn3; float4 nwt;
    uint4 dc0, dc1, dc2, dc3; float4 dwt;
    uint4 dn0, dn1, dn2, dn3; float4 dnwt;
    loadC(0, cc0, cc1, cc2, cc3, cwt, px);
    if (tid < 64) loadC(0, dc0, dc1, dc2, dc3, dwt, px2);
    loadC(1, nn0, nn1, nn2, nn3, nwt, px);
    if (tid < 64) loadC(1, dn0, dn1, dn2, dn3, dnwt, px2);
    dmaA(0, 0);
    __builtin_amdgcn_sched_barrier(0);
    if (wv == 0) { asm volatile("s_waitcnt vmcnt(12)" ::: "memory"); }
    else         { asm volatile("s_waitcnt vmcnt(8)"  ::: "memory"); }
    __builtin_amdgcn_sched_barrier(0);
    interpC(cc0, cc1, cc2, cc3, cwt, BsD, px);
    if (tid < 64) interpC(dc0, dc1, dc2, dc3, dwt, BsD, px2);
    cc0 = nn0; cc1 = nn1; cc2 = nn2; cc3 = nn3; cwt = nwt;
    if (tid < 64) { dc0 = dn0; dc1 = dn1; dc2 = dn2; dc3 = dn3; dwt = dnwt; }
    asm volatile("s_waitcnt lgkmcnt(0)" ::: "memory");
    __builtin_amdgcn_sched_barrier(0);
    __builtin_amdgcn_s_barrier();

    for (int r = 0; r < 36; ++r) {
        const int cur = r & 1;

        if (r <= 33) {
            loadC(r + 2, nn0, nn1, nn2, nn3, nwt, px);
            if (tid < 64) loadC(r + 2, dn0, dn1, dn2, dn3, dnwt, px2);
        }
        if (r <= 34) dmaA(r + 1, cur ^ 1);

        __builtin_amdgcn_sched_barrier(0);
        if (r <= 33) {
            if (wv == 0) { asm volatile("s_waitcnt vmcnt(12)" ::: "memory"); }
            else         { asm volatile("s_waitcnt vmcnt(8)"  ::: "memory"); }
        } else if (r == 34) {
            asm volatile("s_waitcnt vmcnt(4)" ::: "memory");
        } else {
            asm volatile("s_waitcnt vmcnt(0)" ::: "memory");
        }
        __builtin_amdgcn_sched_barrier(0);

        {
            const char* Ac = smem + cur * 32768 + wv * 4096;
            const int sw0 = ((quad ^ (l16 & 7)) * 16);
            const int sw1 = (((4 + quad) ^ (l16 & 7)) * 16);
            bf16x8 af00 = *(const bf16x8*)(Ac + l16 * 128 + sw0);
            bf16x8 af01 = *(const bf16x8*)(Ac + (16 + l16) * 128 + sw0);
            bf16x8 af10 = *(const bf16x8*)(Ac + l16 * 128 + sw1);
            bf16x8 af11 = *(const bf16x8*)(Ac + (16 + l16) * 128 + sw1);
            const unsigned short* Br = BsD + cur * 5760;
#pragma unroll
            for (int nt = 0; nt < 5; ++nt) {
                bf16x8 b0 = *(const bf16x8*)&Br[(nt * 16 + l16) * 72 + quad * 8];
                acc[0][nt] = __builtin_amdgcn_mfma_f32_16x16x32_bf16(af00, b0, acc[0][nt], 0, 0, 0);
                acc[1][nt] = __builtin_amdgcn_mfma_f32_16x16x32_bf16(af01, b0, acc[1][nt], 0, 0, 0);
            }
#pragma unroll
            for (int nt = 0; nt < 5; ++nt) {
                bf16x8 b1 = *(const bf16x8*)&Br[(nt * 16 + l16) * 72 + 32 + quad * 8];
                acc[0][nt] = __builtin_amdgcn_mfma_f32_16x16x32_bf16(af10, b1, acc[0][nt], 0, 0, 0);
                acc[1][nt] = __builtin_amdgcn_mfma_f32_16x16x32_bf16(af11, b1, acc[1][nt], 0, 0, 0);
            }
        }

        if (r <= 34) {
            unsigned short* Bw = BsD + (cur ^ 1) * 5760;
            interpC(cc0, cc1, cc2, cc3, cwt, Bw, px);
            if (tid < 64) interpC(dc0, dc1, dc2, dc3, dwt, Bw, px2);
            cc0 = nn0; cc1 = nn1; cc2 = nn2; cc3 = nn3; cwt = nwt;
            if (tid < 64) { dc0 = dn0; dc1 = dn1; dc2 = dn2; dc3 = dn3; dwt = dnwt; }
        }

        asm volatile("s_waitcnt lgkmcnt(0)" ::: "memory");
        __builtin_amdgcn_sched_barrier(0);
        __builtin_amdgcn_s_barrier();
    }

    asm volatile("s_waitcnt vmcnt(0) lgkmcnt(0)" ::: "memory");
    __syncthreads();

    float* tileS = (float*)smem;
    if (out_mode == 0) {
#pragma unroll
        for (int pass = 0; pass < 4; ++pass) {
            if ((wv >> 1) == pass) {
#pragma unroll
                for (int mt = 0; mt < 2; ++mt)
#pragma unroll
                    for (int nt = 0; nt < 5; ++nt)
#pragma unroll
                        for (int rr = 0; rr < 4; ++rr) {
                            int ml = (wv & 1) * 32 + mt * 16 + quad * 4 + rr;
                            int n  = nt * 16 + l16;
                            tileS[ml * 80 + n] = fmaxf(acc[mt][nt][rr], 0.0f);
                        }
            }
            __syncthreads();
#pragma unroll
            for (int j = 0; j < 3; ++j) {
                int idx = j * 512 + tid;
                if (idx < 1152) {
                    int row = idx / 18, q = idx - row * 18;
                    *(float4*)&out[(size_t)(b * 256 + pass * 64 + row) * PXB + hw0 + q * 4] =
                        *(const float4*)&tileS[row * 80 + q * 4];
                }
            }
            __syncthreads();
        }
    } else {
#pragma unroll
        for (int pass = 0; pass < 5; ++pass) {
#pragma unroll
            for (int mt = 0; mt < 2; ++mt) {
                f32x4 v = acc[mt][pass];
                v[0] = fmaxf(v[0], 0.f); v[1] = fmaxf(v[1], 0.f);
                v[2] = fmaxf(v[2], 0.f); v[3] = fmaxf(v[3], 0.f);
                *(f32x4*)&tileS[l16 * 264 + wv * 32 + mt * 16 + quad * 4] = v;
            }
            __syncthreads();
            const int cnt = (pass < 4) ? 1024 : 512;
#pragma unroll
            for (int j = 0; j < 2; ++j) {
                int idx = j * 512 + tid;
                if (idx < cnt) {
                    int pxl = idx >> 6, ln = idx & 63;
                    float4 v = *(const float4*)&tileS[pxl * 264 + ln * 4];
                    size_t oi = ((size_t)b * PXB + hw0 + pass * 16 + pxl) * 256 + ln * 4;
                    unsigned short hv[4], lv[4];
#pragma unroll
                    for (int e = 0; e < 4; ++e) {
                        float fe = (e == 0) ? v.x : (e == 1) ? v.y : (e == 2) ? v.z : v.w;
                        hv[e] = f2bf(fe);
                        lv[e] = f2bf(fe - bf2f(hv[e]));
                    }
                    *(ushort4*)&outH[oi] = *(ushort4*)hv;
                    *(ushort4*)&outL[oi] = *(ushort4*)lv;
                }
            }
            __syncthreads();
        }
    }
}

// ---------------------------------------------------------------------------
extern "C" void kernel_launch(void* const* d_in, const int* in_sizes, int n_in,
                              void* d_out, int out_size, void* d_ws, size_t ws_size,
                              hipStream_t stream) {
    const float* x     = (const float*)d_in[0];
    const float* woff0 = (const float*)d_in[1];
    const float* boff0 = (const float*)d_in[2];
    const float* w0    = (const float*)d_in[3];
    const float* woff1 = (const float*)d_in[4];
    const float* boff1 = (const float*)d_in[5];
    const float* w1    = (const float*)d_in[6];
    float* out = (float*)d_out;

    char* p = (char*)d_ws;
    float* om  = (float*)p;  p += (size_t)2 * 27 * PXB * 4;               // 2.0 MB
    unsigned short* xh  = (unsigned short*)p; p += (size_t)2 * 256 * PXB * 2;  // 9.4 MB
    unsigned short* xl  = (unsigned short*)p; p += (size_t)2 * 256 * PXB * 2;  // 9.4 MB
    unsigned short* h1h = (unsigned short*)p; p += (size_t)2 * 256 * PXB * 2;  // 9.4 MB
    unsigned short* h1l = (unsigned short*)p; p += (size_t)2 * 256 * PXB * 2;  // 9.4 MB
    unsigned short* wA0 = (unsigned short*)p; p += (size_t)256 * KTOT * 2;
    unsigned short* wA1 = (unsigned short*)p; p += (size_t)256 * KTOT * 2;
    unsigned short* wH0 = (unsigned short*)p; p += (size_t)32 * KTOT * 2;
    unsigned short* wL0 = (unsigned short*)p; p += (size_t)32 * KTOT * 2;
    unsigned short* wH1 = (unsigned short*)p; p += (size_t)32 * KTOT * 2;
    unsigned short* wL1 = (unsigned short*)p; p += (size_t)32 * KTOT * 2;

    hipLaunchKernelGGL(transpose_kernel, dim3(PXB / 64, 4, 2), dim3(256), 0, stream, x, xh, xl);
    hipLaunchKernelGGL(prep_w_kernel, dim3(256 * KTOT / 256), dim3(256), 0, stream, w0, wA0);
    hipLaunchKernelGGL(prep_w_kernel, dim3(256 * KTOT / 256), dim3(256), 0, stream, w1, wA1);
    hipLaunchKernelGGL(prep_woff_kernel, dim3(32 * KTOT / 256), dim3(256), 0, stream, woff0, wH0, wL0);
    hipLaunchKernelGGL(prep_woff_kernel, dim3(32 * KTOT / 256), dim3(256), 0, stream, woff1, wH1, wL1);

    // Layer 0: x -> h1 (NHWC hi/lo bf16)
    hipLaunchKernelGGL(offconv_v3, dim3(576), dim3(256), 0, stream, xh, xl, wH0, wL0, boff0, om);
    hipLaunchKernelGGL(dfconv_v6, dim3(256), dim3(512), 0, stream, xh, om, wA0,
                       (float*)nullptr, h1h, h1l, 1);

    // Layer 1: h1 -> out (NCHW fp32)
    hipLaunchKernelGGL(offconv_v3, dim3(576), dim3(256), 0, stream, h1h, h1l, wH1, wL1, boff1, om);
    hipLaunchKernelGGL(dfconv_v6, dim3(256), dim3(512), 0, stream, h1h, om, wA1,
                       out, (unsigned short*)nullptr, (unsigned short*)nullptr, 0);
}